// Round 6
// baseline (267.638 us; speedup 1.0000x reference)
//
#include <hip/hip_runtime.h>

// SSIM (16,3,512,512) f32. Fused separable 11x11 Gaussian + SSIM + mean.
// R6: occupancy fix. LDS union: staged inputs sx (14.8KB) and h-pass output
// buffers (26.9KB) share one 26.9KB region; h-results live in registers
// across an extra barrier. LDS 41.9->26.9KB => 4-6 blocks/CU (was 3).
// h-fields packed float4(mu1,mu2,e11,e22)+float2(d) -> v-pass 2 LDS reads/row.
// No device fences in main kernel (R5 lesson); separate finalize kernel.

#define KSZ   11
#define PAD   5
#define TILE  32
#define HALO  42               // TILE + KSZ - 1
#define SXW   44               // sx row stride in float2
#define NT    256
#define NBX   16
#define NBY   16
#define NPLANES 48
#define NBLOCKS (NBX * NBY * NPLANES)
#define NSLOT  (HALO * 16)     // 672 h-slots

struct W11 { float w[KSZ]; };
struct HRes { float2 m0, m1, e0, e1; float d0, d1; };

static __device__ __forceinline__ float fast_rcp(float x) {
#if __has_builtin(__builtin_amdgcn_rcpf)
    return __builtin_amdgcn_rcpf(x);
#else
    return 1.0f / x;
#endif
}

// Horizontal 11-tap for one slot (row r, output cols 2g,2g+1). Results in regs.
static __device__ __forceinline__ HRes hslot(const float2* sxp, const W11& wk, int s) {
    const int r  = s >> 4;
    const int g  = s & 15;
    const float2* row = sxp + r * SXW + 2 * g;
    const float2 x0 = row[0],  x1 = row[1],  x2 = row[2],  x3 = row[3];
    const float2 x4 = row[4],  x5 = row[5],  x6 = row[6],  x7 = row[7];
    const float2 x8 = row[8],  x9 = row[9],  x10 = row[10], x11 = row[11];
    HRes o;
    o.m0 = make_float2(0.f, 0.f); o.m1 = make_float2(0.f, 0.f);
    o.e0 = make_float2(0.f, 0.f); o.e1 = make_float2(0.f, 0.f);
    o.d0 = 0.f; o.d1 = 0.f;
#define HTAP(K, A, B)                                                   \
    {                                                                   \
        const float w = wk.w[K];                                        \
        o.m0.x += w * (A).x;       o.m0.y += w * (A).y;                 \
        o.e0.x += w * (A).x*(A).x; o.e0.y += w * (A).y*(A).y;           \
        o.d0   += w * (A).x*(A).y;                                      \
        o.m1.x += w * (B).x;       o.m1.y += w * (B).y;                 \
        o.e1.x += w * (B).x*(B).x; o.e1.y += w * (B).y*(B).y;           \
        o.d1   += w * (B).x*(B).y;                                      \
    }
    HTAP(0,  x0,  x1)  HTAP(1,  x1,  x2)  HTAP(2,  x2,  x3)
    HTAP(3,  x3,  x4)  HTAP(4,  x4,  x5)  HTAP(5,  x5,  x6)
    HTAP(6,  x6,  x7)  HTAP(7,  x7,  x8)  HTAP(8,  x8,  x9)
    HTAP(9,  x9,  x10) HTAP(10, x10, x11)
#undef HTAP
    return o;
}

static __device__ __forceinline__ void hwrite(float4* hA, float* hD, const HRes& o, int s) {
    const int r = s >> 4;
    const int g = s & 15;
    const int base = r * TILE + 2 * g;
    hA[base]     = make_float4(o.m0.x, o.m0.y, o.e0.x, o.e0.y);
    hA[base + 1] = make_float4(o.m1.x, o.m1.y, o.e1.x, o.e1.y);
    *(float2*)(hD + base) = make_float2(o.d0, o.d1);
}

__global__ __launch_bounds__(NT)
void ssim_fused(const float* __restrict__ img1,
                const float* __restrict__ img2,
                const float* __restrict__ window,
                double* __restrict__ acc)
{
    // Union: phase A = sx (42*44 float2 = 14784B); phase B = hA (42*32 float4
    // = 21504B) + hD (42*32 float = 5376B). Total 26880B.
    __shared__ __align__(16) float smem[HALO * TILE * 5];
    __shared__ float k1d[KSZ];
    __shared__ float red[NT / 64];
    float2* sx = (float2*)smem;
    float4* hA = (float4*)smem;
    float*  hD = smem + HALO * TILE * 4;

    const int tid = threadIdx.x;
    const int bx = blockIdx.x * TILE;
    const int by = blockIdx.y * TILE;
    const size_t planeOff = (size_t)blockIdx.z * 512 * 512;
    const float* p1 = img1 + planeOff;
    const float* p2 = img2 + planeOff;

    // 1D kernel = row sums of the 2D window (window = outer(k,k), sum(k)=1).
    if (tid < KSZ) {
        float s = 0.f;
        #pragma unroll
        for (int j = 0; j < KSZ; ++j) s += window[tid * KSZ + j];
        k1d[tid] = s;
    }

    // Stage halo tile (zero outside image = zero padding), b64 LDS writes.
    for (int idx = tid; idx < HALO * HALO; idx += NT) {
        const int r = idx / HALO;
        const int c = idx - r * HALO;
        const int gr = by + r - PAD;
        const int gc = bx + c - PAD;
        float v1 = 0.f, v2 = 0.f;
        if (((unsigned)gr < 512u) && ((unsigned)gc < 512u)) {
            const size_t g = (size_t)gr * 512 + gc;
            v1 = p1[g];
            v2 = p2[g];
        }
        sx[r * SXW + c] = make_float2(v1, v2);
    }
    __syncthreads();

    W11 wk;
    #pragma unroll
    for (int k = 0; k < KSZ; ++k) wk.w[k] = k1d[k];   // constant indices only

    // ---- Horizontal pass into registers (3 slots/thread; slot2 partial).
    const bool has2 = (tid + 512) < NSLOT;
    const HRes rA = hslot(sx, wk, tid);
    const HRes rB = hslot(sx, wk, tid + 256);
    HRes rC;
    if (has2) rC = hslot(sx, wk, tid + 512);
    __syncthreads();   // everyone done READING sx

    hwrite(hA, hD, rA, tid);
    hwrite(hA, hD, rB, tid + 256);
    if (has2) hwrite(hA, hD, rC, tid + 512);
    __syncthreads();   // h-buffers ready

    // ---- Vertical pass: thread = (col vc, 4-row group vr0). Named accums.
    const float C1f = 1e-4f;
    const float C2f = 9e-4f;
    float lsum = 0.f;
    {
        const int vc  = tid & 31;
        const int vr0 = (tid >> 5) * 4;

        float2 mu0 = make_float2(0.f,0.f), mu1 = make_float2(0.f,0.f),
               mu2 = make_float2(0.f,0.f), mu3 = make_float2(0.f,0.f);
        float2 ee0 = make_float2(0.f,0.f), ee1 = make_float2(0.f,0.f),
               ee2 = make_float2(0.f,0.f), ee3 = make_float2(0.f,0.f);
        float  dd0 = 0.f, dd1 = 0.f, dd2 = 0.f, dd3 = 0.f;

#define VTAP(J, I, MU, EE, DD)                                          \
        if ((J) >= (I) && (J) - (I) < KSZ) {                            \
            const float w = wk.w[((J) >= (I)) ? (J) - (I) : 0];         \
            MU.x += w * a.x; MU.y += w * a.y;                           \
            EE.x += w * a.z; EE.y += w * a.w;                           \
            DD   += w * dv;                                             \
        }
#define VROW(J)                                                         \
        {                                                               \
            const int hr = vr0 + (J);                                   \
            const float4 a  = hA[hr * TILE + vc];                       \
            const float  dv = hD[hr * TILE + vc];                       \
            VTAP(J, 0, mu0, ee0, dd0)                                   \
            VTAP(J, 1, mu1, ee1, dd1)                                   \
            VTAP(J, 2, mu2, ee2, dd2)                                   \
            VTAP(J, 3, mu3, ee3, dd3)                                   \
        }
        VROW(0)  VROW(1)  VROW(2)  VROW(3)  VROW(4)  VROW(5)  VROW(6)
        VROW(7)  VROW(8)  VROW(9)  VROW(10) VROW(11) VROW(12) VROW(13)
#undef VROW
#undef VTAP

#define SSIMI(MU, EE, DD)                                               \
        {                                                               \
            const float mu1v = MU.x, mu2v = MU.y;                       \
            const float mu1sq = mu1v * mu1v;                            \
            const float mu2sq = mu2v * mu2v;                            \
            const float mu12  = mu1v * mu2v;                            \
            const float s11 = EE.x - mu1sq;                             \
            const float s22 = EE.y - mu2sq;                             \
            const float s12 = DD   - mu12;                              \
            const float num = (2.f * mu12 + C1f) * (2.f * s12 + C2f);   \
            const float den = (mu1sq + mu2sq + C1f) * (s11 + s22 + C2f);\
            lsum += num * fast_rcp(den);                                \
        }
        SSIMI(mu0, ee0, dd0)
        SSIMI(mu1, ee1, dd1)
        SSIMI(mu2, ee2, dd2)
        SSIMI(mu3, ee3, dd3)
#undef SSIMI
    }

    // ---- Block reduction -> ONE device-scope atomic per block. No fence.
    #pragma unroll
    for (int off = 32; off > 0; off >>= 1)
        lsum += __shfl_down(lsum, off, 64);
    const int wave = tid >> 6;
    const int lane = tid & 63;
    if (lane == 0) red[wave] = lsum;
    __syncthreads();
    if (tid == 0) {
        const float bsum = red[0] + red[1] + red[2] + red[3];
        atomicAdd(acc, (double)bsum);
    }
}

__global__ __launch_bounds__(64)
void ssim_finalize(const double* __restrict__ acc, float* __restrict__ out) {
    if (threadIdx.x == 0)
        out[0] = (float)(acc[0] * (1.0 / ((double)NBLOCKS * TILE * TILE)));
}

extern "C" void kernel_launch(void* const* d_in, const int* in_sizes, int n_in,
                              void* d_out, int out_size, void* d_ws, size_t ws_size,
                              hipStream_t stream) {
    const float* img1   = (const float*)d_in[0];
    const float* img2   = (const float*)d_in[1];
    const float* window = (const float*)d_in[2];
    float* out = (float*)d_out;
    double* acc = (double*)d_ws;

    hipMemsetAsync(d_ws, 0, 8, stream);

    dim3 grid(NBX, NBY, NPLANES);
    ssim_fused<<<grid, NT, 0, stream>>>(img1, img2, window, acc);
    ssim_finalize<<<1, 64, 0, stream>>>(acc, out);
}